// Round 5
// baseline (698.506 us; speedup 1.0000x reference)
//
#include <hip/hip_runtime.h>
#include <hip/hip_bf16.h>

// B=32, S=256, E=32, D=32. ALL DEVICE BUFFERS FP32 (reference dtypes).
// x = seq.reshape(32, 8192); Q/K/V = x @ W^T + b   (W: [8192,8192] row-major)
// attn = exp(QK^T)/(rowsum+1e-5) [no max-sub]; out = (attn @ V)/sqrt(32)
//
// ROUND 5: R4 hit the per-CU GLL return-path cap: W 805 MB + A 403 MB =
// 1.21 GB / 217 us = 5.57 TB/s ~= 9.3 B/cyc/CU (m13 ceiling ~10). A was
// stealing 1/3 of the W budget. R2 evidence: VGPR-path loads of L2-resident
// A ran at 7 TB/s ON TOP of W. Fix: A via inline-asm global_load_dwordx4
// into VGPRs (reg-double-buffered, 2x-unrolled loop), counted manually in
// the same vmcnt stream (COMPUTE has zero VMEM -> vmcnt(4) exact).
// W pipeline unchanged from R4 (3-buf GLL, raw s_barrier, counted vmcnt).
// LDS 48 KB -> 3 blocks/CU (12 waves/CU, up from 8).
// Accuracy: bf16 hi/lo 3-term scheme unchanged.

#define FIN  8192
#define FOUT 8192
#define SD   8192
#define KSPLIT 4
#define KCHUNK 2048            // FIN / KSPLIT
#define BK 64                  // floats staged per W row per stage (256 B)
#define NT 64                  // W rows per block tile
#define NSTG (KCHUNK / BK)     // 32 stages per block (even: 2x unroll ok)
#define BUFF (NT * BK)         // 4096 floats = 16 KB per W buffer

typedef __attribute__((ext_vector_type(8))) short bf16x8;   // 8 bf16 (4 VGPRs)
typedef __attribute__((ext_vector_type(4))) float f32x4;

struct Areg { bf16x8 f[8]; };  // 8 frags = {h0,h1,l0,l1} x {il0,il1}, 32 VGPRs

static __device__ __forceinline__ short bf16_hi(float w, float& hf) {
    __hip_bfloat16 h = __float2bfloat16(w);      // RNE
    hf = __bfloat162float(h);
    return *(short*)&h;
}
static __device__ __forceinline__ short bf16_of(float w) {
    __hip_bfloat16 h = __float2bfloat16(w);
    return *(short*)&h;
}

static __device__ __forceinline__ void gload_lds16(const float* g, float* l) {
    __builtin_amdgcn_global_load_lds(
        (const __attribute__((address_space(1))) float*)g,
        (__attribute__((address_space(3))) float*)l, 16, 0, 0);
}

// ---------------------------------------------------------------------------
// Kernel 0: split fp32 x -> bf16 hi/lo, written PRE-SWIZZLED in MFMA fragment
// order: buffer[i_step][lane][8] with lane=(quad<<4)|r16 holding
// x[rb*16+r16][i*32+quad*8 .. +8].  Also bias-primes Q/K/V for the split-K
// atomic combine.
// ---------------------------------------------------------------------------
__global__ __launch_bounds__(256) void split_x_init(
    const float* __restrict__ x,
    short* __restrict__ xh0, short* __restrict__ xh1,
    short* __restrict__ xl0, short* __restrict__ xl1,
    const float* __restrict__ bq, const float* __restrict__ bk,
    const float* __restrict__ bv,
    float* __restrict__ Qf, float* __restrict__ Kf, float* __restrict__ Vf)
{
    const int u = blockIdx.x * 256 + threadIdx.x;      // 0..65535
    if (u < 32768) {
        const int r16 = u & 15;
        const int q   = (u >> 4) & 3;
        const int rb  = (u >> 6) & 1;
        const int i   = u >> 7;                        // k-step 0..255
        const int row = rb * 16 + r16;                 // x row 0..31
        const float4* src = (const float4*)(x + (size_t)row * FIN) + (i * 8 + q * 2);
        float4 a  = src[0];
        float4 b2 = src[1];
        float wf[8] = {a.x, a.y, a.z, a.w, b2.x, b2.y, b2.z, b2.w};
        short hb[8], lb[8];
        #pragma unroll
        for (int j = 0; j < 8; ++j) {
            float hf;
            hb[j] = bf16_hi(wf[j], hf);
            lb[j] = bf16_of(wf[j] - hf);               // exact residual
        }
        bf16x8 vh = {hb[0],hb[1],hb[2],hb[3],hb[4],hb[5],hb[6],hb[7]};
        bf16x8 vl = {lb[0],lb[1],lb[2],lb[3],lb[4],lb[5],lb[6],lb[7]};
        short* dh = rb ? xh1 : xh0;
        short* dl = rb ? xl1 : xl0;
        const int ci = i * 64 + (u & 63);              // (u&63) == quad*16+r16
        ((bf16x8*)dh)[ci] = vh;
        ((bf16x8*)dl)[ci] = vl;
    }
    // bias prime: u covers [32][2048] float4 per matrix
    const int col4 = u & 2047;
    ((float4*)Qf)[u] = ((const float4*)bq)[col4];
    ((float4*)Kf)[u] = ((const float4*)bk)[col4];
    ((float4*)Vf)[u] = ((const float4*)bv)[col4];
}

// ---------------------------------------------------------------------------
// Kernel 1: fused QKV GEMM. W: 3-buf GLL pipeline (counted vmcnt, no drain).
// A: asm global_load_dwordx4 -> VGPRs (L2-resident, separate path budget),
// register double-buffer, 1 stage ahead.
// Grid: 3 mats x 128 n-tiles(64 rows) x 4 kc = 1536 blocks x 256 thr.
// LDS 48 KB -> 3 blocks/CU, 12 waves/CU.
// Per iter t: wait vmcnt(4) [W(t)+A(t) landed; W(t+1):4 flying]; s_barrier;
//   sched_barrier; LOADA(A(t+1)):8; STAGE_W(t+2):4; COMPUTE(t).
// ---------------------------------------------------------------------------
__global__ __launch_bounds__(256) void qkv_gemm(
    const short* __restrict__ xh0, const short* __restrict__ xh1,
    const short* __restrict__ xl0, const short* __restrict__ xl1,
    const float* __restrict__ Wq, const float* __restrict__ Wk,
    const float* __restrict__ Wv,
    float* __restrict__ outQ, float* __restrict__ outK, float* __restrict__ outV)
{
    __shared__ float Ws[3 * BUFF];         // 48 KB, W only

    const int tid  = threadIdx.x;
    const int wave = tid >> 6;
    const int lane = tid & 63;
    const int quad = lane >> 4;
    const int r16  = lane & 15;

    const int bid   = blockIdx.x;          // 0..1535
    const int which = bid >> 9;            // 0=Q 1=K 2=V
    const int rem   = bid & 511;
    const int kc    = rem >> 7;            // 0..3 k-chunk
    const int nt    = rem & 127;           // 0..127 n-tile (64 rows)

    const float* W; float* out;
    if (which == 0)      { W = Wq; out = outQ; }
    else if (which == 1) { W = Wk; out = outK; }
    else                 { W = Wv; out = outV; }

    const size_t wrow_base = (size_t)(nt * 64 + wave * 16) * FIN + (size_t)kc * KCHUNK;
    const int   ldsrow = wave * 16 + r16;
    const int   swz    = (r16 & 7) << 4;
    const int   kc64   = kc * (KCHUNK / 32);          // k-step base of chunk
    const int   lane16 = lane * 16;                   // byte offset in frag row

    f32x4 acc0 = {0.f, 0.f, 0.f, 0.f};
    f32x4 acc1 = {0.f, 0.f, 0.f, 0.f};

    // W stage: 4 GLL/wave, rows j*4+quad of the 16-row panel, 256 B runs,
    // source XOR-preswizzled (rule 21: linear LDS dest == swizzled layout).
    auto STAGE = [&](float* buf, int s) {
        #pragma unroll
        for (int j = 0; j < 4; ++j) {
            const int row   = j * 4 + quad;
            const int sbyte = (r16 * 16) ^ ((row & 7) << 4);
            const float* src = W + wrow_base + (size_t)row * FIN + s * BK + (sbyte >> 2);
            float* dst = buf + (wave * 16 + j * 4) * BK;          // wave-uniform
            gload_lds16(src, dst);
        }
    };

    // A load: 8 asm global_load_dwordx4 (1 KB wave-contiguous each, L2-hot).
    // f[kind*2+il]: kind 0..3 = {h rows0-15, h rows16-31, l rows0-15, l 16-31}.
    auto LOADA = [&](Areg& A, int s) {
        const size_t off = ((size_t)(kc64 + s * 2) << 10) + lane16;
        const char* p0 = (const char*)xh0 + off;
        const char* p1 = (const char*)xh1 + off;
        const char* p2 = (const char*)xl0 + off;
        const char* p3 = (const char*)xl1 + off;
        asm volatile(
            "global_load_dwordx4 %0, %8, off\n\t"
            "global_load_dwordx4 %1, %8, off offset:1024\n\t"
            "global_load_dwordx4 %2, %9, off\n\t"
            "global_load_dwordx4 %3, %9, off offset:1024\n\t"
            "global_load_dwordx4 %4, %10, off\n\t"
            "global_load_dwordx4 %5, %10, off offset:1024\n\t"
            "global_load_dwordx4 %6, %11, off\n\t"
            "global_load_dwordx4 %7, %11, off offset:1024"
            : "=&v"(A.f[0]), "=&v"(A.f[2]), "=&v"(A.f[1]), "=&v"(A.f[3]),
              "=&v"(A.f[4]), "=&v"(A.f[6]), "=&v"(A.f[5]), "=&v"(A.f[7])
            : "v"(p0), "v"(p1), "v"(p2), "v"(p3)
            : "memory");
        // note operand order above: %0=f[0](h0 il0) %1=f[2](h0 il1 -> +1024),
        // %2=f[1](h1 il0) %3=f[3](h1 il1), %4=f[4](l0 il0) %5=f[6](l0 il1),
        // %6=f[5](l1 il0) %7=f[7](l1 il1)
    };

    // COMPUTE: pure LDS + VALU + MFMA (zero VMEM => vmcnt stays exact).
    // frag index: il*? -> ah0=f[il*1+0]? mapping: f[il*4..]? see LOADA:
    // f[0]=h0il0 f[1]=h1il0 f[2]=h0il1 f[3]=h1il1 f[4]=l0il0 f[5]=l1il0
    // f[6]=l0il1 f[7]=l1il1  => ah0=f[il*2+0], ah1=f[il*2+1],
    //                           al0=f[4+il*2+0], al1=f[4+il*2+1]
    auto COMPUTE = [&](const float* buf, const Areg& A) {
        const char* WsB = (const char*)buf + ldsrow * (BK * 4);   // 256 B rows
        #pragma unroll
        for (int il = 0; il < 2; ++il) {
            bf16x8 ah0 = A.f[il * 2 + 0];
            bf16x8 ah1 = A.f[il * 2 + 1];
            bf16x8 al0 = A.f[4 + il * 2 + 0];
            bf16x8 al1 = A.f[4 + il * 2 + 1];

            const int koff = il * 128 + quad * 32;
            f32x4 w0 = *(const f32x4*)(WsB + ((koff     ) ^ swz));
            f32x4 w1 = *(const f32x4*)(WsB + ((koff + 16) ^ swz));

            float wf[8] = {w0[0], w0[1], w0[2], w0[3], w1[0], w1[1], w1[2], w1[3]};
            short hb[8], lb[8];
            #pragma unroll
            for (int j = 0; j < 8; ++j) {
                float hf;
                hb[j] = bf16_hi(wf[j], hf);
                lb[j] = bf16_of(wf[j] - hf);
            }
            bf16x8 wh = {hb[0],hb[1],hb[2],hb[3],hb[4],hb[5],hb[6],hb[7]};
            bf16x8 wl = {lb[0],lb[1],lb[2],lb[3],lb[4],lb[5],lb[6],lb[7]};

            acc0 = __builtin_amdgcn_mfma_f32_16x16x32_bf16(ah0, wh, acc0, 0, 0, 0);
            acc0 = __builtin_amdgcn_mfma_f32_16x16x32_bf16(al0, wh, acc0, 0, 0, 0);
            acc0 = __builtin_amdgcn_mfma_f32_16x16x32_bf16(ah0, wl, acc0, 0, 0, 0);
            acc1 = __builtin_amdgcn_mfma_f32_16x16x32_bf16(ah1, wh, acc1, 0, 0, 0);
            acc1 = __builtin_amdgcn_mfma_f32_16x16x32_bf16(al1, wh, acc1, 0, 0, 0);
            acc1 = __builtin_amdgcn_mfma_f32_16x16x32_bf16(ah1, wl, acc1, 0, 0, 0);
        }
    };

    // K-phase stagger (MFMA accumulate is order-independent).
    const int phase = (bid * 13) & (NSTG - 1);
    auto idx = [&](int u) { return (phase + u) & (NSTG - 1); };

    float* wb0 = Ws;
    float* wb1 = Ws + BUFF;
    float* wb2 = Ws + 2 * BUFF;

    Areg Aev, Aod;

    // Prologue: A(0):8 then W(0):4, W(1):4  -> wait(4) at t=0 forces A0+W0.
    LOADA(Aev, idx(0));
    STAGE(wb0, idx(0));
    STAGE(wb1, idx(1));

    // One iteration; t parity selects the A register buffer (compile-time
    // via 2x manual unroll -> no runtime-indexed reg arrays, rule 20).
    auto QITER = [&](int t, Areg& Ac, Areg& An) {
        if (t == NSTG - 1) { asm volatile("s_waitcnt vmcnt(0)" ::: "memory"); }
        else               { asm volatile("s_waitcnt vmcnt(4)" ::: "memory"); }
        __builtin_amdgcn_s_barrier();          // all waves done compute(t-1)
        __builtin_amdgcn_sched_barrier(0);     // rule 18: no hoist past wait
        if (t + 1 < NSTG) LOADA(An, idx(t + 1));
        if (t + 2 < NSTG) STAGE(wb2, idx(t + 2));
        COMPUTE(wb0, Ac);
        float* tmp = wb0; wb0 = wb1; wb1 = wb2; wb2 = tmp;
    };

    #pragma unroll 1
    for (int tt = 0; tt < NSTG; tt += 2) {
        QITER(tt,     Aev, Aod);
        QITER(tt + 1, Aod, Aev);
    }

    // C/D layout (m89): col = lane&15, row = quad*4 + reg.
    // atomicAdd into bias-primed out (split-K combine).
    const int n = nt * 64 + wave * 16 + r16;
    #pragma unroll
    for (int i = 0; i < 4; ++i) {
        const int m = quad * 4 + i;
        atomicAdd(&out[(size_t)m        * FOUT + n], acc0[i]);
        atomicAdd(&out[(size_t)(m + 16) * FOUT + n], acc1[i]);
    }
}

// ---------------------------------------------------------------------------
// Kernel 2: attention, fp32, single pass (no max subtraction — faithful).
// grid = 32 batches x 8 row-tiles(32) = 256 blocks, 512 thr (16 t-chunks).
// Partial buffers padded (stride 33/17) to kill 64-way LDS bank conflicts.
// ---------------------------------------------------------------------------
#define PZS 33
#define PDS 17
__global__ __launch_bounds__(512) void attention(
    const float* __restrict__ Qf, const float* __restrict__ Kf,
    const float* __restrict__ Vf, float* __restrict__ out)
{
    __shared__ float smem[16896 + 544];     // max(K|V 16384, pz 16896) + pden
    float* Ks = smem;
    float* Vs = smem + SD;

    const int b     = blockIdx.x >> 3;
    const int stile = blockIdx.x & 7;
    const int tid   = threadIdx.x;

    const float* Kb = Kf + (size_t)b * SD;
    const float* Vb = Vf + (size_t)b * SD;
    for (int i = tid; i < SD / 4; i += 512) {        // 4 iters each
        ((float4*)Ks)[i] = ((const float4*)Kb)[i];
        ((float4*)Vs)[i] = ((const float4*)Vb)[i];
    }
    __syncthreads();

    const int srow  = tid & 31;
    const int chunk = tid >> 5;             // 0..15, each covers 16 t's
    const int s     = stile * 32 + srow;

    float q[32];
    const float* Qrow = Qf + (size_t)b * SD + (size_t)s * 32;
    #pragma unroll
    for (int d = 0; d < 32; ++d) q[d] = Qrow[d];

    float z[32];
    #pragma unroll
    for (int d = 0; d < 32; ++d) z[d] = 0.f;
    float den = 0.f;

    const int t0 = chunk * 16;
    for (int t = t0; t < t0 + 16; ++t) {
        const float* krow = Ks + t * 32;
        float scr = 0.f;
        #pragma unroll
        for (int d = 0; d < 32; ++d) scr += q[d] * krow[d];
        const float e = __expf(scr);
        den += e;
        const float* vrow = Vs + t * 32;
        #pragma unroll
        for (int d = 0; d < 32; ++d) z[d] += e * vrow[d];
    }

    __syncthreads();                        // done reading Ks/Vs
    float* pz   = smem;                     // [32*16][33]
    float* pden = smem + 16896;             // [32][17]
    #pragma unroll
    for (int d = 0; d < 32; ++d) pz[(srow * 16 + chunk) * PZS + d] = z[d];
    pden[srow * PDS + chunk] = den;
    __syncthreads();

    const int row = tid >> 4;               // 0..31
    const int dq  = tid & 15;               // 0..15 -> 2 output floats
    float dsum = 0.f;
    #pragma unroll
    for (int c = 0; c < 16; ++c) dsum += pden[row * PDS + c];
    const float inv = 0.17677669529663687f / (dsum + 1e-5f);  // (1/sqrt(32))/(den+eps)

    const int so = stile * 32 + row;
    float* orow = out + (size_t)b * SD + (size_t)so * 32 + dq * 2;
    #pragma unroll
    for (int j = 0; j < 2; ++j) {
        float zz = 0.f;
        #pragma unroll
        for (int c = 0; c < 16; ++c) zz += pz[(row * 16 + c) * PZS + dq * 2 + j];
        orow[j] = zz * inv;
    }
}

// ---------------------------------------------------------------------------
extern "C" void kernel_launch(void* const* d_in, const int* in_sizes, int n_in,
                              void* d_out, int out_size, void* d_ws, size_t ws_size,
                              hipStream_t stream)
{
    const float* x  = (const float*)d_in[0];
    const float* Wq = (const float*)d_in[1];
    const float* bq = (const float*)d_in[2];
    const float* Wk = (const float*)d_in[3];
    const float* bk = (const float*)d_in[4];
    const float* Wv = (const float*)d_in[5];
    const float* bv = (const float*)d_in[6];
    float* out = (float*)d_out;

    // ws: xh0|xh1|xl0|xl1 (4 x 256KB fragment-order) | Qf | Kf | Vf  = 4 MB
    short* xh0 = (short*)d_ws;
    short* xh1 = xh0 + 131072;
    short* xl0 = xh1 + 131072;
    short* xl1 = xl0 + 131072;
    float* Qf = (float*)((char*)d_ws + (1u << 20));
    float* Kf = Qf + 262144;
    float* Vf = Kf + 262144;

    split_x_init<<<256, 256, 0, stream>>>(x, xh0, xh1, xl0, xl1,
                                          bq, bk, bv, Qf, Kf, Vf);
    qkv_gemm    <<<1536, 256, 0, stream>>>(xh0, xh1, xl0, xl1,
                                           Wq, Wk, Wv, Qf, Kf, Vf);
    attention   <<<256, 512, 0, stream>>>(Qf, Kf, Vf, out);
}